// Round 4
// baseline (504.844 us; speedup 1.0000x reference)
//
#include <hip/hip_runtime.h>
#include <math.h>

#define NSWEEP 6

// ---------------------------------------------------------------------------
// Kernel 1: partial max-pooled outer products. Grid = B*G blocks.
// ---------------------------------------------------------------------------
__global__ __launch_bounds__(256) void pool_kernel(const float* __restrict__ x,
                                                   float* __restrict__ part,
                                                   int G) {
  __shared__ float xs[4096];
  const int t = threadIdx.x;
  const int blk = blockIdx.x;
  const int b = blk / G, g = blk % G;
  const int npb = 4096 / G;
  const int ntile = npb >> 6;
  const int n0 = g * npb;
  const int i0 = (t >> 4) * 4;
  const int j0 = (t & 15) * 4;

  float mv[4][4];
#pragma unroll
  for (int a = 0; a < 4; ++a)
#pragma unroll
    for (int c = 0; c < 4; ++c) mv[a][c] = -INFINITY;

  const float4* src = reinterpret_cast<const float4*>(x + ((size_t)b * 4096 + n0) * 64);
  float4* xs4 = reinterpret_cast<float4*>(xs);

  for (int tile = 0; tile < ntile; ++tile) {
#pragma unroll
    for (int q = 0; q < 4; ++q) xs4[t + 256 * q] = src[(size_t)tile * 1024 + t + 256 * q];
    __syncthreads();
#pragma unroll 4
    for (int n = 0; n < 64; ++n) {
      const float4 vi = *reinterpret_cast<const float4*>(&xs[n * 64 + i0]);
      const float4 vj = *reinterpret_cast<const float4*>(&xs[n * 64 + j0]);
      const float fi[4] = {vi.x, vi.y, vi.z, vi.w};
      const float fj[4] = {vj.x, vj.y, vj.z, vj.w};
#pragma unroll
      for (int a = 0; a < 4; ++a)
#pragma unroll
        for (int c = 0; c < 4; ++c)
          mv[a][c] = fmaxf(mv[a][c], fi[a] * fj[c]);
    }
    __syncthreads();
  }

#pragma unroll
  for (int a = 0; a < 4; ++a)
#pragma unroll
    for (int c = 0; c < 4; ++c)
      xs[(i0 + a) * 64 + (j0 + c)] = mv[a][c];
  __syncthreads();

  float* dst = part + ((size_t)b * G + g) * 4096;
#pragma unroll
  for (int q = 0; q < 16; ++q) dst[t + 256 * q] = xs[t + 256 * q];
}

// ---------------------------------------------------------------------------
// Kernel 2: systolic one-sided Jacobi SVD.
// wave0: G columns (full, in regs), computes (c,s), barrier-free rounds.
// wave1: V consumer, replays (c,s) from LDS ring (release/acquire sync).
// waves 2,3: park, then help epilogue GEMM.
// Slots: lane l owns slot l; pairing is always (k, k+32); columns migrate by
// fixed permutation tau (circle method) via ds_bpermute with constant addr.
// ---------------------------------------------------------------------------
__device__ __forceinline__ float bperm(int byteaddr, float v) {
  return __int_as_float(__builtin_amdgcn_ds_bpermute(byteaddr, __float_as_int(v)));
}

__global__ __launch_bounds__(256, 1) void svd_kernel(const float* __restrict__ part,
                                                     float* __restrict__ out, int G) {
  __shared__ __align__(16) float Wl[64 * 68];
  __shared__ __align__(16) float Vl[64 * 68];
  __shared__ float2 ring[64][64];
  __shared__ float red[4];
  __shared__ int pflag_s, cflag_s;

  const int b = blockIdx.x;
  const int t = threadIdx.x;
  const int wave = t >> 6, lane = t & 63;

  if (t == 0) { pflag_s = 0; cflag_s = 0; }

  // ---- fused max-reduce of partials into Wl (stride 68), all 256 threads ----
  const float4* p4 = reinterpret_cast<const float4*>(part) + (size_t)b * G * 1024;
  float4 acc[4];
#pragma unroll
  for (int u = 0; u < 4; ++u) acc[u] = p4[t + 256 * u];
#pragma unroll 2
  for (int g = 1; g < G; ++g) {
#pragma unroll
    for (int u = 0; u < 4; ++u) {
      const float4 v = p4[(size_t)g * 1024 + t + 256 * u];
      acc[u].x = fmaxf(acc[u].x, v.x);
      acc[u].y = fmaxf(acc[u].y, v.y);
      acc[u].z = fmaxf(acc[u].z, v.z);
      acc[u].w = fmaxf(acc[u].w, v.w);
    }
  }
#pragma unroll
  for (int u = 0; u < 4; ++u) {
    const int idx = t + 256 * u;
    const int i = idx >> 4;
    const int j = (idx & 15) * 4;
    *reinterpret_cast<float4*>(&Wl[i * 68 + j]) = acc[u];
  }
  __syncthreads();

  // migration source slot: tau^{-1}(lane)
  int srcM;
  if (lane == 0) srcM = 0;
  else if (lane == 1) srcM = 32;
  else if (lane <= 31) srcM = lane - 1;
  else if (lane == 63) srcM = 31;
  else srcM = lane + 1;
  const int addrM = srcM << 2;
  const int addrX = (lane ^ 32) << 2;
  const float roleSgn = (lane < 32) ? 1.0f : -1.0f;

  if (wave == 0) {
    // ================= producer: G columns =================
    float g[64], ex[64];
#pragma unroll
    for (int k = 0; k < 64; ++k) g[k] = Wl[k * 68 + lane];

    int rg = 0;
    float a = 0.0f;
    for (int sweep = 0; sweep < NSWEEP; ++sweep) {
      // exact column-norm refresh
      float s0 = 0, s1 = 0, s2 = 0, s3 = 0;
#pragma unroll
      for (int k = 0; k < 64; k += 4) {
        s0 = fmaf(g[k], g[k], s0);
        s1 = fmaf(g[k + 1], g[k + 1], s1);
        s2 = fmaf(g[k + 2], g[k + 2], s2);
        s3 = fmaf(g[k + 3], g[k + 3], s3);
      }
      a = (s0 + s1) + (s2 + s3);

      for (int r = 0; r < 63; ++r) {
        // pair exchange (constant addr, 2-way bank alias = free)
#pragma unroll
        for (int k = 0; k < 64; ++k) ex[k] = bperm(addrX, g[k]);
        const float bb = bperm(addrX, a);

        float d0 = 0, d1 = 0, d2 = 0, d3 = 0;
#pragma unroll
        for (int k = 0; k < 64; k += 4) {
          d0 = fmaf(g[k], ex[k], d0);
          d1 = fmaf(g[k + 1], ex[k + 1], d1);
          d2 = fmaf(g[k + 2], ex[k + 2], d2);
          d3 = fmaf(g[k + 3], ex[k + 3], d3);
        }
        const float d = (d0 + d1) + (d2 + d3);  // identical on both pair lanes

        // angle: t = d*sgn(u)/(|u|+sqrt(u^2+d^2)); u exactly negates on partner
        const float u = (bb - a) * 0.5f;
        const float sg = (u != 0.0f) ? copysignf(1.0f, u) : roleSgn;
        const float h = sqrtf(fmaf(u, u, d * d));
        const float tt = (d == 0.0f) ? 0.0f : (d * sg) / (fabsf(u) + h);
        const float c = rsqrtf(fmaf(tt, tt, 1.0f));
        const float s = tt * c;

        // publish (c,s) early so the consumer unblocks
        ring[rg & 63][lane] = make_float2(c, s);
        if (lane == 0)
          __hip_atomic_store(&pflag_s, rg + 1, __ATOMIC_RELEASE, __HIP_MEMORY_SCOPE_WORKGROUP);

        // rotate + exact norm update
        const float ns = -s;
#pragma unroll
        for (int k = 0; k < 64; ++k) g[k] = fmaf(ns, ex[k], c * g[k]);
        a = fmaf(c * c, a, fmaf(s * s, bb, -2.0f * (c * s) * d));

        // lap guard (ring depth 64, consumer publishes every 16)
        if ((rg & 15) == 0 && rg >= 48) {
          while (rg - __hip_atomic_load(&cflag_s, __ATOMIC_ACQUIRE, __HIP_MEMORY_SCOPE_WORKGROUP) >= 48)
            __builtin_amdgcn_s_sleep(1);
        }

        // migrate columns (and their tracked norms) to next slots
#pragma unroll
        for (int k = 0; k < 64; ++k) g[k] = bperm(addrM, g[k]);
        a = bperm(addrM, a);
        ++rg;
      }
    }

    // exact sigma; W = G * diag(sigma^{-1/2})
    float s0 = 0, s1 = 0, s2 = 0, s3 = 0;
#pragma unroll
    for (int k = 0; k < 64; k += 4) {
      s0 = fmaf(g[k], g[k], s0);
      s1 = fmaf(g[k + 1], g[k + 1], s1);
      s2 = fmaf(g[k + 2], g[k + 2], s2);
      s3 = fmaf(g[k + 3], g[k + 3], s3);
    }
    const float sig2 = (s0 + s1) + (s2 + s3);
    const float sigma = sqrtf(sig2);
    const float coef = (sigma > 1e-30f) ? rsqrtf(sigma) : 0.0f;
#pragma unroll
    for (int k = 0; k < 64; ++k) Wl[k * 68 + lane] = g[k] * coef;

  } else if (wave == 1) {
    // ================= consumer: V columns =================
    float v[64], ex[64];
#pragma unroll
    for (int k = 0; k < 64; ++k) v[k] = (k == lane) ? 1.0f : 0.0f;

    for (int rg = 0; rg < NSWEEP * 63; ++rg) {
      // issue exchange first; it overlaps the flag spin
#pragma unroll
      for (int k = 0; k < 64; ++k) ex[k] = bperm(addrX, v[k]);

      while (__hip_atomic_load(&pflag_s, __ATOMIC_ACQUIRE, __HIP_MEMORY_SCOPE_WORKGROUP) < rg + 1)
        __builtin_amdgcn_s_sleep(1);
      const float2 cs = ring[rg & 63][lane];

      const float c = cs.x, ns = -cs.y;
#pragma unroll
      for (int k = 0; k < 64; ++k) v[k] = fmaf(ns, ex[k], c * v[k]);
#pragma unroll
      for (int k = 0; k < 64; ++k) v[k] = bperm(addrM, v[k]);

      if ((rg & 15) == 15 && lane == 0)
        __hip_atomic_store(&cflag_s, rg + 1, __ATOMIC_RELEASE, __HIP_MEMORY_SCOPE_WORKGROUP);
    }
#pragma unroll
    for (int k = 0; k < 64; ++k) Vl[k * 68 + lane] = v[k];
  }
  // waves 2,3 fall through to here and park
  __syncthreads();

  // ---- R = W * V^T; each wave computes 16 columns for all 64 rows ----
  float wr[64];
#pragma unroll
  for (int jb = 0; jb < 16; ++jb) {
    const float4 v = *reinterpret_cast<const float4*>(&Wl[lane * 68 + jb * 4]);
    wr[4 * jb] = v.x; wr[4 * jb + 1] = v.y; wr[4 * jb + 2] = v.z; wr[4 * jb + 3] = v.w;
  }
  __syncthreads();  // Wl free for R

  const int j0 = wave * 16;
  float rvals[16];
  float ssq = 0.0f;
#pragma unroll 4
  for (int jj = 0; jj < 16; ++jj) {
    const float4* vr = reinterpret_cast<const float4*>(&Vl[(j0 + jj) * 68]);
    float c0 = 0, c1 = 0, c2 = 0, c3 = 0;
#pragma unroll
    for (int kb = 0; kb < 16; ++kb) {
      const float4 vv = vr[kb];
      c0 = fmaf(wr[4 * kb], vv.x, c0);
      c1 = fmaf(wr[4 * kb + 1], vv.y, c1);
      c2 = fmaf(wr[4 * kb + 2], vv.z, c2);
      c3 = fmaf(wr[4 * kb + 3], vv.w, c3);
    }
    const float accv = (c0 + c1) + (c2 + c3);  // R[lane][j0+jj]
    rvals[jj] = accv;
    ssq = fmaf(accv, accv, ssq);
  }
#pragma unroll
  for (int jj = 0; jj < 4; ++jj)
    *reinterpret_cast<float4*>(&Wl[lane * 68 + j0 + 4 * jj]) =
        make_float4(rvals[4 * jj], rvals[4 * jj + 1], rvals[4 * jj + 2], rvals[4 * jj + 3]);

#pragma unroll
  for (int off = 32; off; off >>= 1) ssq += __shfl_xor(ssq, off, 64);
  if (lane == 0) red[wave] = ssq;
  __syncthreads();
  const float rn = rsqrtf(fmaxf(red[0] + red[1] + red[2] + red[3], 1e-24f));

#pragma unroll
  for (int u = 0; u < 16; ++u) {
    const int e = t + 256 * u;
    out[(size_t)b * 4096 + e] = Wl[(e >> 6) * 68 + (e & 63)] * rn;
  }
}

extern "C" void kernel_launch(void* const* d_in, const int* in_sizes, int n_in,
                              void* d_out, int out_size, void* d_ws, size_t ws_size,
                              hipStream_t stream) {
  const float* x = (const float*)d_in[0];
  float* out = (float*)d_out;
  float* part = (float*)d_ws;

  int G = 32;
  while (G > 1 && (size_t)16 * G * 4096 * 4 > ws_size) G >>= 1;

  pool_kernel<<<dim3(16 * G), dim3(256), 0, stream>>>(x, part, G);
  svd_kernel<<<dim3(16), dim3(256), 0, stream>>>(part, out, G);
}

// Round 6
// 326.389 us; speedup vs baseline: 1.5468x; 1.5468x over previous
//
#include <hip/hip_runtime.h>
#include <math.h>

#define NSWEEP 6
#define NR (NSWEEP * 63)

// ---------------------------------------------------------------------------
// Kernel 1: partial max-pooled outer products. Grid = B*G blocks.
// ---------------------------------------------------------------------------
__global__ __launch_bounds__(256) void pool_kernel(const float* __restrict__ x,
                                                   float* __restrict__ part,
                                                   int G) {
  __shared__ float xs[4096];
  const int t = threadIdx.x;
  const int blk = blockIdx.x;
  const int b = blk / G, g = blk % G;
  const int npb = 4096 / G;
  const int ntile = npb >> 6;
  const int n0 = g * npb;
  const int i0 = (t >> 4) * 4;
  const int j0 = (t & 15) * 4;

  float mv[4][4];
#pragma unroll
  for (int a = 0; a < 4; ++a)
#pragma unroll
    for (int c = 0; c < 4; ++c) mv[a][c] = -INFINITY;

  const float4* src = reinterpret_cast<const float4*>(x + ((size_t)b * 4096 + n0) * 64);
  float4* xs4 = reinterpret_cast<float4*>(xs);

  for (int tile = 0; tile < ntile; ++tile) {
#pragma unroll
    for (int q = 0; q < 4; ++q) xs4[t + 256 * q] = src[(size_t)tile * 1024 + t + 256 * q];
    __syncthreads();
#pragma unroll 4
    for (int n = 0; n < 64; ++n) {
      const float4 vi = *reinterpret_cast<const float4*>(&xs[n * 64 + i0]);
      const float4 vj = *reinterpret_cast<const float4*>(&xs[n * 64 + j0]);
      const float fi[4] = {vi.x, vi.y, vi.z, vi.w};
      const float fj[4] = {vj.x, vj.y, vj.z, vj.w};
#pragma unroll
      for (int a = 0; a < 4; ++a)
#pragma unroll
        for (int c = 0; c < 4; ++c)
          mv[a][c] = fmaxf(mv[a][c], fi[a] * fj[c]);
    }
    __syncthreads();
  }

#pragma unroll
  for (int a = 0; a < 4; ++a)
#pragma unroll
    for (int c = 0; c < 4; ++c)
      xs[(i0 + a) * 64 + (j0 + c)] = mv[a][c];
  __syncthreads();

  float* dst = part + ((size_t)b * G + g) * 4096;
#pragma unroll
  for (int q = 0; q < 16; ++q) dst[t + 256 * q] = xs[t + 256 * q];
}

// ---------------------------------------------------------------------------
// Kernel 2: one-sided Jacobi SVD.
//   wave0 (producer): G columns, fused rotate+next-exchange, writes (c,s) to
//     a 64-slot LDS ring; release-publish once per 16 rounds.
//   wave1 (consumer): V replay from the ring, same fused structure; publishes
//     progress once per 16 rounds (producer guard slack 40 -> no overwrite).
//   waves 2,3: park, then all 4 waves do the R = W*V^T epilogue (R3-proven).
// ---------------------------------------------------------------------------
__device__ __forceinline__ float bperm(int byteaddr, float v) {
  return __int_as_float(__builtin_amdgcn_ds_bpermute(byteaddr, __float_as_int(v)));
}

__device__ __forceinline__ int partner_of(int lane, int r) {
  if (lane == 0) { int q = 62 + r; if (q >= 63) q -= 63; return 1 + q; }
  int u = lane - 1 - r; if (u < 0) u += 63;
  if (u == 62) return 0;
  int m = 61 - u + r; if (m >= 63) m -= 63; return 1 + m;
}

__global__ __launch_bounds__(256, 1) void svd_kernel(const float* __restrict__ part,
                                                     float* __restrict__ out, int G) {
  __shared__ __align__(16) float Al[64 * 68];   // pooled A -> W -> R
  __shared__ __align__(16) float Vl[64 * 68];   // final V
  __shared__ float2 ring[64][64];               // (c,s) per round slot per lane
  __shared__ float red[4];
  __shared__ int pflag_s, cflag_s;

  const int b = blockIdx.x;
  const int t = threadIdx.x;
  const int wave = t >> 6, lane = t & 63;

  if (t == 0) { pflag_s = 0; cflag_s = 0; }

  // ---- prologue: fused max-reduce of partials into Al (all 256 threads) ----
  const float4* p4 = reinterpret_cast<const float4*>(part) + (size_t)b * G * 1024;
  float4 acc[4];
#pragma unroll
  for (int u = 0; u < 4; ++u) acc[u] = p4[t + 256 * u];
#pragma unroll 2
  for (int g = 1; g < G; ++g) {
#pragma unroll
    for (int u = 0; u < 4; ++u) {
      const float4 v = p4[(size_t)g * 1024 + t + 256 * u];
      acc[u].x = fmaxf(acc[u].x, v.x);
      acc[u].y = fmaxf(acc[u].y, v.y);
      acc[u].z = fmaxf(acc[u].z, v.z);
      acc[u].w = fmaxf(acc[u].w, v.w);
    }
  }
#pragma unroll
  for (int u = 0; u < 4; ++u) {
    const int idx = t + 256 * u;
    const int i = idx >> 4;
    const int j = (idx & 15) * 4;
    *reinterpret_cast<float4*>(&Al[i * 68 + j]) = acc[u];
  }
  __syncthreads();

  if (wave == 0) {
    // ================= producer: G columns =================
    float g[64], ex[64];
#pragma unroll
    for (int k = 0; k < 64; ++k) g[k] = Al[k * 68 + lane];

    float n0 = 0, n1 = 0, n2 = 0, n3 = 0;
#pragma unroll
    for (int k = 0; k < 64; k += 4) {
      n0 = fmaf(g[k], g[k], n0);
      n1 = fmaf(g[k + 1], g[k + 1], n1);
      n2 = fmaf(g[k + 2], g[k + 2], n2);
      n3 = fmaf(g[k + 3], g[k + 3], n3);
    }
    float a = (n0 + n1) + (n2 + n3);

    int rr = 0;
    int partner = partner_of(lane, 0);
    int addr = partner << 2;
#pragma unroll
    for (int k = 0; k < 64; ++k) ex[k] = bperm(addr, g[k]);
    float bb = bperm(addr, a);

    for (int rg = 0; rg < NR; ++rg) {
      // dot product (identical accumulation order on both pair lanes)
      float d0 = 0, d1 = 0, d2 = 0, d3 = 0;
#pragma unroll
      for (int k = 0; k < 64; k += 4) {
        d0 = fmaf(g[k], ex[k], d0);
        d1 = fmaf(g[k + 1], ex[k + 1], d1);
        d2 = fmaf(g[k + 2], ex[k + 2], d2);
        d3 = fmaf(g[k + 3], ex[k + 3], d3);
      }
      const float d = (d0 + d1) + (d2 + d3);

      const float u = (bb - a) * 0.5f;                       // exactly negated on partner
      const float sg = (u != 0.0f) ? copysignf(1.0f, u)
                                   : ((lane < partner) ? 1.0f : -1.0f);
      const float h = sqrtf(fmaf(u, u, d * d));
      const float tt = (d == 0.0f) ? 0.0f : (d * sg) / (fabsf(u) + h);
      const float c = rsqrtf(fmaf(tt, tt, 1.0f));            // identical both lanes
      const float s = tt * c;                                // opposite sign on partner
      const float ns = -s;

      ring[rg & 63][lane] = make_float2(c, s);               // plain ds_write
      if ((rg & 15) == 15 && lane == 0)
        __hip_atomic_store(&pflag_s, rg + 1, __ATOMIC_RELEASE, __HIP_MEMORY_SCOPE_WORKGROUP);

      const float aupd = fmaf(c * c, a, fmaf(s * s, bb, -2.0f * (c * s) * d));

      rr = (rr == 62) ? 0 : rr + 1;
      partner = partner_of(lane, rr);
      addr = partner << 2;

      // fused: rotate own column, immediately issue next round's exchange
#pragma unroll
      for (int k = 0; k < 64; ++k) {
        g[k] = fmaf(ns, ex[k], c * g[k]);
        ex[k] = bperm(addr, g[k]);
      }

      if (rr == 0) {  // sweep boundary: exact norm refresh
        float m0 = 0, m1 = 0, m2 = 0, m3 = 0;
#pragma unroll
        for (int k = 0; k < 64; k += 4) {
          m0 = fmaf(g[k], g[k], m0);
          m1 = fmaf(g[k + 1], g[k + 1], m1);
          m2 = fmaf(g[k + 2], g[k + 2], m2);
          m3 = fmaf(g[k + 3], g[k + 3], m3);
        }
        a = (m0 + m1) + (m2 + m3);
      } else {
        a = aupd;
      }
      bb = bperm(addr, a);

      // lap guard: ring holds 64 slots; keep producer <= 56 ahead (40 + 16)
      if ((rg & 15) == 15) {
        int cd = __hip_atomic_load(&cflag_s, __ATOMIC_ACQUIRE, __HIP_MEMORY_SCOPE_WORKGROUP);
        while (rg + 1 - cd > 40) {
          __builtin_amdgcn_s_sleep(2);
          cd = __hip_atomic_load(&cflag_s, __ATOMIC_ACQUIRE, __HIP_MEMORY_SCOPE_WORKGROUP);
        }
      }
    }
    if (lane == 0)
      __hip_atomic_store(&pflag_s, NR, __ATOMIC_RELEASE, __HIP_MEMORY_SCOPE_WORKGROUP);

    // exact sigma; W = G * diag(sigma^{-1/2}) into Al
    float m0 = 0, m1 = 0, m2 = 0, m3 = 0;
#pragma unroll
    for (int k = 0; k < 64; k += 4) {
      m0 = fmaf(g[k], g[k], m0);
      m1 = fmaf(g[k + 1], g[k + 1], m1);
      m2 = fmaf(g[k + 2], g[k + 2], m2);
      m3 = fmaf(g[k + 3], g[k + 3], m3);
    }
    const float sig2 = (m0 + m1) + (m2 + m3);
    const float sigma = sqrtf(sig2);
    const float coef = (sigma > 1e-30f) ? rsqrtf(sigma) : 0.0f;
#pragma unroll
    for (int k = 0; k < 64; ++k) Al[k * 68 + lane] = g[k] * coef;

  } else if (wave == 1) {
    // ================= consumer: V columns (replay) =================
    float v[64], ex[64];
#pragma unroll
    for (int k = 0; k < 64; ++k) v[k] = (k == lane) ? 1.0f : 0.0f;

    int rr = 0;
    int partner = partner_of(lane, 0);
    int addr = partner << 2;
#pragma unroll
    for (int k = 0; k < 64; ++k) ex[k] = bperm(addr, v[k]);

    int seen = 0;
    for (int rg = 0; rg < NR; ++rg) {
      if (seen < rg + 1) {
        for (;;) {
          seen = __hip_atomic_load(&pflag_s, __ATOMIC_ACQUIRE, __HIP_MEMORY_SCOPE_WORKGROUP);
          if (seen >= rg + 1) break;
          __builtin_amdgcn_s_sleep(2);
        }
      }
      const float2 cs = ring[rg & 63][lane];
      const float c = cs.x, ns = -cs.y;

      rr = (rr == 62) ? 0 : rr + 1;
      partner = partner_of(lane, rr);
      addr = partner << 2;

#pragma unroll
      for (int k = 0; k < 64; ++k) {
        v[k] = fmaf(ns, ex[k], c * v[k]);
        ex[k] = bperm(addr, v[k]);
      }

      if ((rg & 15) == 15 && lane == 0)
        __hip_atomic_store(&cflag_s, rg + 1, __ATOMIC_RELEASE, __HIP_MEMORY_SCOPE_WORKGROUP);
    }
#pragma unroll
    for (int k = 0; k < 64; ++k) Vl[k * 68 + lane] = v[k];
  }
  // waves 2,3 park here
  __syncthreads();

  // ---- R = W * V^T; each wave computes 16 columns for all 64 rows ----
  float wr[64];
#pragma unroll
  for (int jb = 0; jb < 16; ++jb) {
    const float4 v = *reinterpret_cast<const float4*>(&Al[lane * 68 + jb * 4]);
    wr[4 * jb] = v.x; wr[4 * jb + 1] = v.y; wr[4 * jb + 2] = v.z; wr[4 * jb + 3] = v.w;
  }
  __syncthreads();  // all snapshots taken; Al rows free for R

  const int j0 = wave * 16;
  float rvals[16];
  float ssq = 0.0f;
#pragma unroll 4
  for (int jj = 0; jj < 16; ++jj) {
    const float4* vr = reinterpret_cast<const float4*>(&Vl[(j0 + jj) * 68]);
    float c0 = 0, c1 = 0, c2 = 0, c3 = 0;
#pragma unroll
    for (int kb = 0; kb < 16; ++kb) {
      const float4 vv = vr[kb];   // broadcast: conflict-free
      c0 = fmaf(wr[4 * kb], vv.x, c0);
      c1 = fmaf(wr[4 * kb + 1], vv.y, c1);
      c2 = fmaf(wr[4 * kb + 2], vv.z, c2);
      c3 = fmaf(wr[4 * kb + 3], vv.w, c3);
    }
    const float accv = (c0 + c1) + (c2 + c3);  // R[lane][j0+jj]
    rvals[jj] = accv;
    ssq = fmaf(accv, accv, ssq);
  }
#pragma unroll
  for (int jj = 0; jj < 4; ++jj)
    *reinterpret_cast<float4*>(&Al[lane * 68 + j0 + 4 * jj]) =
        make_float4(rvals[4 * jj], rvals[4 * jj + 1], rvals[4 * jj + 2], rvals[4 * jj + 3]);

  // ---- ||R||_F^2 reduction, normalize, coalesced store ----
#pragma unroll
  for (int off = 32; off; off >>= 1) ssq += __shfl_xor(ssq, off, 64);
  if (lane == 0) red[wave] = ssq;
  __syncthreads();
  const float rn = rsqrtf(fmaxf(red[0] + red[1] + red[2] + red[3], 1e-24f));

#pragma unroll
  for (int u = 0; u < 16; ++u) {
    const int e = t + 256 * u;
    out[(size_t)b * 4096 + e] = Al[(e >> 6) * 68 + (e & 63)] * rn;
  }
}

extern "C" void kernel_launch(void* const* d_in, const int* in_sizes, int n_in,
                              void* d_out, int out_size, void* d_ws, size_t ws_size,
                              hipStream_t stream) {
  const float* x = (const float*)d_in[0];
  float* out = (float*)d_out;
  float* part = (float*)d_ws;

  int G = 32;
  while (G > 1 && (size_t)16 * G * 4096 * 4 > ws_size) G >>= 1;

  pool_kernel<<<dim3(16 * G), dim3(256), 0, stream>>>(x, part, G);
  svd_kernel<<<dim3(16), dim3(256), 0, stream>>>(part, out, G);
}